// Round 1
// baseline (1102.103 us; speedup 1.0000x reference)
//
#include <hip/hip_runtime.h>
#include <hip/hip_bf16.h>

#define HIDDEN 64
#define EPS 1e-5f

// ---------------- CSR build ----------------

__global__ void hist_kernel(const int* __restrict__ row, int* __restrict__ cnt, int e) {
    int i = blockIdx.x * blockDim.x + threadIdx.x;
    if (i < e) atomicAdd(&cnt[row[i]], 1);
}

// single-block exclusive scan of cnt[0..n) -> row_ptr[0..n]
__global__ __launch_bounds__(1024) void scan_kernel(const int* __restrict__ cnt,
                                                    int* __restrict__ row_ptr, int n) {
    __shared__ int wsum[16];
    __shared__ int wexcl[16];
    __shared__ int chunk_total;
    __shared__ int carry_s;
    int tid = threadIdx.x;
    int lane = tid & 63;
    int w = tid >> 6;
    if (tid == 0) carry_s = 0;
    __syncthreads();
    for (int base = 0; base < n; base += 1024) {
        int i = base + tid;
        int v = (i < n) ? cnt[i] : 0;
        // inclusive scan within wave
        int sc = v;
#pragma unroll
        for (int off = 1; off < 64; off <<= 1) {
            int t = __shfl_up(sc, off, 64);
            if (lane >= off) sc += t;
        }
        if (lane == 63) wsum[w] = sc;
        __syncthreads();
        if (w == 0) {
            int t = (lane < 16) ? wsum[lane] : 0;
            int s2 = t;
#pragma unroll
            for (int off = 1; off < 16; off <<= 1) {
                int u = __shfl_up(s2, off, 64);
                if (lane >= off) s2 += u;
            }
            if (lane < 16) wexcl[lane] = s2 - t;
            if (lane == 15) chunk_total = s2;
        }
        __syncthreads();
        int c = carry_s;
        if (i < n) row_ptr[i] = c + wexcl[w] + (sc - v);
        __syncthreads();
        if (tid == 0) carry_s += chunk_total;
        __syncthreads();
    }
    if (tid == 0) row_ptr[n] = carry_s;
}

__global__ void fill_kernel(const int* __restrict__ row, const int* __restrict__ col,
                            const int* __restrict__ row_ptr, int* __restrict__ cnt,
                            int* __restrict__ ecol, int e) {
    int i = blockIdx.x * blockDim.x + threadIdx.x;
    if (i < e) {
        int r = row[i];
        int pos = row_ptr[r] + atomicAdd(&cnt[r], 1);
        ecol[pos] = col[i];
    }
}

// transpose 2L weight matrices (64x64): wt[m][k][o] = w[m][o][k]
__global__ void transpose_kernel(const float* __restrict__ cw, const float* __restrict__ hw,
                                 float* __restrict__ wt, int L) {
    int idx = blockIdx.x * blockDim.x + threadIdx.x;
    int total = 2 * L * 4096;
    if (idx >= total) return;
    int mat = idx >> 12;
    int k = (idx >> 6) & 63;
    int o = idx & 63;
    const float* src = (mat < L) ? (cw + (size_t)mat * 4096) : (hw + (size_t)(mat - L) * 4096);
    wt[idx] = src[o * 64 + k];
}

// ---------------- layer kernels ----------------

// m[node] = relu(h[node] @ w^T), wt is w^T laid out [k][o]
__global__ __launch_bounds__(256, 2) void mm_relu_kernel(const float* __restrict__ h,
                                                         const float* __restrict__ wt,
                                                         float* __restrict__ out, int n) {
    int node = blockIdx.x * blockDim.x + threadIdx.x;
    if (node >= n) return;
    const float4* h4 = (const float4*)(h + (size_t)node * HIDDEN);
    float4 hv[16];
#pragma unroll
    for (int j = 0; j < 16; j++) hv[j] = h4[j];
    float acc[64];
#pragma unroll
    for (int o = 0; o < 64; o++) acc[o] = 0.f;
#pragma unroll
    for (int k4 = 0; k4 < 16; k4++) {
        float4 hk = hv[k4];
#pragma unroll
        for (int kk = 0; kk < 4; kk++) {
            float hs = (kk == 0) ? hk.x : (kk == 1) ? hk.y : (kk == 2) ? hk.z : hk.w;
            const float4* w4 = (const float4*)(wt + (size_t)(k4 * 4 + kk) * 64);
#pragma unroll
            for (int j = 0; j < 16; j++) {
                float4 wv = w4[j];
                acc[4 * j + 0] = fmaf(hs, wv.x, acc[4 * j + 0]);
                acc[4 * j + 1] = fmaf(hs, wv.y, acc[4 * j + 1]);
                acc[4 * j + 2] = fmaf(hs, wv.z, acc[4 * j + 2]);
                acc[4 * j + 3] = fmaf(hs, wv.w, acc[4 * j + 3]);
            }
        }
    }
    float4* o4 = (float4*)(out + (size_t)node * HIDDEN);
#pragma unroll
    for (int j = 0; j < 16; j++) {
        float4 v;
        v.x = fmaxf(acc[4 * j + 0], 0.f);
        v.y = fmaxf(acc[4 * j + 1], 0.f);
        v.z = fmaxf(acc[4 * j + 2], 0.f);
        v.w = fmaxf(acc[4 * j + 3], 0.f);
        o4[j] = v;
    }
}

// out[node] = rmsnorm(h[node] + sum_{e in CSR[node]} m[ecol[e]], nw)
// wave per node, lane = channel
__global__ __launch_bounds__(256) void aggregate_kernel(const float* __restrict__ h,
                                                        const float* __restrict__ m,
                                                        const int* __restrict__ row_ptr,
                                                        const int* __restrict__ ecol,
                                                        const float* __restrict__ nw,
                                                        float* __restrict__ out, int n) {
    int lane = threadIdx.x & 63;
    int wave = (blockIdx.x * blockDim.x + threadIdx.x) >> 6;
    int nwaves = (gridDim.x * blockDim.x) >> 6;
    float scale = nw[lane];
    for (int node = wave; node < n; node += nwaves) {
        int beg = row_ptr[node];
        int end = row_ptr[node + 1];
        float s = h[(size_t)node * HIDDEN + lane];
        for (int e = beg; e < end; e++) {
            int c = ecol[e];
            s += m[(size_t)c * HIDDEN + lane];
        }
        float ss = s * s;
#pragma unroll
        for (int off = 32; off > 0; off >>= 1) ss += __shfl_xor(ss, off, 64);
        float inv = rsqrtf(ss * (1.0f / 64.0f) + EPS);
        out[(size_t)node * HIDDEN + lane] = s * inv * scale;
    }
}

// h[node] = rmsnorm(h[node] + relu(h[node] @ w^T), nw)   (in place)
__global__ __launch_bounds__(256, 2) void hidden_kernel(float* __restrict__ h,
                                                        const float* __restrict__ wt,
                                                        const float* __restrict__ nw, int n) {
    int node = blockIdx.x * blockDim.x + threadIdx.x;
    if (node >= n) return;
    float4* h4 = (float4*)(h + (size_t)node * HIDDEN);
    float4 hv[16];
#pragma unroll
    for (int j = 0; j < 16; j++) hv[j] = h4[j];
    float acc[64];
#pragma unroll
    for (int o = 0; o < 64; o++) acc[o] = 0.f;
#pragma unroll
    for (int k4 = 0; k4 < 16; k4++) {
        float4 hk = hv[k4];
#pragma unroll
        for (int kk = 0; kk < 4; kk++) {
            float hs = (kk == 0) ? hk.x : (kk == 1) ? hk.y : (kk == 2) ? hk.z : hk.w;
            const float4* w4 = (const float4*)(wt + (size_t)(k4 * 4 + kk) * 64);
#pragma unroll
            for (int j = 0; j < 16; j++) {
                float4 wv = w4[j];
                acc[4 * j + 0] = fmaf(hs, wv.x, acc[4 * j + 0]);
                acc[4 * j + 1] = fmaf(hs, wv.y, acc[4 * j + 1]);
                acc[4 * j + 2] = fmaf(hs, wv.z, acc[4 * j + 2]);
                acc[4 * j + 3] = fmaf(hs, wv.w, acc[4 * j + 3]);
            }
        }
    }
    // s = h + relu(y); rmsnorm in registers
    float s[64];
    float sumsq = 0.f;
#pragma unroll
    for (int j = 0; j < 16; j++) {
        float4 hk = hv[j];
        s[4 * j + 0] = hk.x + fmaxf(acc[4 * j + 0], 0.f);
        s[4 * j + 1] = hk.y + fmaxf(acc[4 * j + 1], 0.f);
        s[4 * j + 2] = hk.z + fmaxf(acc[4 * j + 2], 0.f);
        s[4 * j + 3] = hk.w + fmaxf(acc[4 * j + 3], 0.f);
        sumsq += s[4 * j + 0] * s[4 * j + 0];
        sumsq += s[4 * j + 1] * s[4 * j + 1];
        sumsq += s[4 * j + 2] * s[4 * j + 2];
        sumsq += s[4 * j + 3] * s[4 * j + 3];
    }
    float inv = rsqrtf(sumsq * (1.0f / 64.0f) + EPS);
#pragma unroll
    for (int j = 0; j < 16; j++) {
        float4 v;
        v.x = s[4 * j + 0] * inv * nw[4 * j + 0];
        v.y = s[4 * j + 1] * inv * nw[4 * j + 1];
        v.z = s[4 * j + 2] * inv * nw[4 * j + 2];
        v.w = s[4 * j + 3] * inv * nw[4 * j + 3];
        h4[j] = v;
    }
}

// ---------------- launch ----------------

static inline size_t align_up(size_t x, size_t a) { return (x + a - 1) & ~(a - 1); }

extern "C" void kernel_launch(void* const* d_in, const int* in_sizes, int n_in,
                              void* d_out, int out_size, void* d_ws, size_t ws_size,
                              hipStream_t stream) {
    const float* x       = (const float*)d_in[0];
    const float* conv_w  = (const float*)d_in[1];
    const float* conv_nw = (const float*)d_in[2];
    const float* hid_w   = (const float*)d_in[3];
    const float* hid_nw  = (const float*)d_in[4];
    const int*   row     = (const int*)d_in[5];
    const int*   col     = (const int*)d_in[6];
    float* out = (float*)d_out;

    const int n = in_sizes[0] / HIDDEN;   // 100000
    const int e = in_sizes[5];            // 800000
    const int L = in_sizes[1] / 4096;     // 4

    // workspace layout
    size_t off = 0;
    char* ws = (char*)d_ws;
    float* wt = (float*)(ws + off);      off = align_up(off + (size_t)2 * L * 4096 * 4, 16);
    float* m = (float*)(ws + off);       off = align_up(off + (size_t)n * HIDDEN * 4, 16);
    int* row_ptr = (int*)(ws + off);     off = align_up(off + (size_t)(n + 1) * 4, 16);
    int* cnt = (int*)(ws + off);         off = align_up(off + (size_t)n * 4, 16);
    int* ecol = (int*)(ws + off);        off = align_up(off + (size_t)e * 4, 16);

    // CSR build (edges constant across layers -> build once per launch)
    hipMemsetAsync(cnt, 0, (size_t)n * 4, stream);
    hist_kernel<<<(e + 255) / 256, 256, 0, stream>>>(row, cnt, e);
    scan_kernel<<<1, 1024, 0, stream>>>(cnt, row_ptr, n);
    hipMemsetAsync(cnt, 0, (size_t)n * 4, stream);
    fill_kernel<<<(e + 255) / 256, 256, 0, stream>>>(row, col, row_ptr, cnt, ecol, e);

    // pre-transpose weights to [k][o]
    transpose_kernel<<<(2 * L * 4096 + 255) / 256, 256, 0, stream>>>(conv_w, hid_w, wt, L);

    const int mm_blocks = (n + 255) / 256;
    const float* hin = x;
    for (int l = 0; l < L; l++) {
        mm_relu_kernel<<<mm_blocks, 256, 0, stream>>>(hin, wt + (size_t)l * 4096, m, n);
        aggregate_kernel<<<1024, 256, 0, stream>>>(hin, m, row_ptr, ecol,
                                                   conv_nw + (size_t)l * HIDDEN, out, n);
        hidden_kernel<<<mm_blocks, 256, 0, stream>>>(out, wt + (size_t)(L + l) * 4096,
                                                     hid_nw + (size_t)l * HIDDEN, n);
        hin = out;
    }
}

// Round 2
// 669.717 us; speedup vs baseline: 1.6456x; 1.6456x over previous
//
#include <hip/hip_runtime.h>
#include <hip/hip_bf16.h>

#define HIDDEN 64
#define EPS 1e-5f

// ---------------- CSR build ----------------

__global__ void hist_kernel(const int* __restrict__ row, int* __restrict__ cnt, int e) {
    int i = blockIdx.x * blockDim.x + threadIdx.x;
    if (i < e) atomicAdd(&cnt[row[i]], 1);
}

// ---- parallel exclusive scan of cnt[0..n) -> row_ptr[0..n], 3 kernels ----

// per-block sums: bsum[b] = sum(cnt[b*256 .. b*256+255])
__global__ __launch_bounds__(256) void block_sum_kernel(const int* __restrict__ cnt,
                                                        int* __restrict__ bsum, int n) {
    __shared__ int wsum[4];
    int tid = threadIdx.x;
    int i = blockIdx.x * 256 + tid;
    int v = (i < n) ? cnt[i] : 0;
#pragma unroll
    for (int off = 32; off > 0; off >>= 1) v += __shfl_xor(v, off, 64);
    if ((tid & 63) == 0) wsum[tid >> 6] = v;
    __syncthreads();
    if (tid == 0) bsum[blockIdx.x] = wsum[0] + wsum[1] + wsum[2] + wsum[3];
}

// single block: exclusive scan of bsum[0..nb), also writes total to *total_out
__global__ __launch_bounds__(1024) void scan_bsum_kernel(int* __restrict__ bsum, int nb,
                                                         int* __restrict__ total_out) {
    __shared__ int wsum[16];
    __shared__ int wexcl[16];
    int tid = threadIdx.x;
    int lane = tid & 63;
    int w = tid >> 6;
    int v = (tid < nb) ? bsum[tid] : 0;
    int sc = v;
#pragma unroll
    for (int off = 1; off < 64; off <<= 1) {
        int t = __shfl_up(sc, off, 64);
        if (lane >= off) sc += t;
    }
    if (lane == 63) wsum[w] = sc;
    __syncthreads();
    if (tid == 0) {
        int a = 0;
#pragma unroll
        for (int j = 0; j < 16; j++) { wexcl[j] = a; a += wsum[j]; }
        *total_out = a;
    }
    __syncthreads();
    if (tid < nb) bsum[tid] = wexcl[w] + (sc - v);
}

// per-block scan + add block offset -> row_ptr
__global__ __launch_bounds__(256) void scan_final_kernel(const int* __restrict__ cnt,
                                                         const int* __restrict__ bexcl,
                                                         int* __restrict__ row_ptr, int n) {
    __shared__ int wsum[4];
    __shared__ int wexcl[4];
    int tid = threadIdx.x;
    int lane = tid & 63;
    int w = tid >> 6;
    int i = blockIdx.x * 256 + tid;
    int v = (i < n) ? cnt[i] : 0;
    int sc = v;
#pragma unroll
    for (int off = 1; off < 64; off <<= 1) {
        int t = __shfl_up(sc, off, 64);
        if (lane >= off) sc += t;
    }
    if (lane == 63) wsum[w] = sc;
    __syncthreads();
    if (tid == 0) {
        int a = 0;
#pragma unroll
        for (int j = 0; j < 4; j++) { wexcl[j] = a; a += wsum[j]; }
    }
    __syncthreads();
    if (i < n) row_ptr[i] = bexcl[blockIdx.x] + wexcl[w] + (sc - v);
}

__global__ void fill_kernel(const int* __restrict__ row, const int* __restrict__ col,
                            const int* __restrict__ row_ptr, int* __restrict__ cnt,
                            int* __restrict__ ecol, int e) {
    int i = blockIdx.x * blockDim.x + threadIdx.x;
    if (i < e) {
        int r = row[i];
        int pos = row_ptr[r] + atomicAdd(&cnt[r], 1);
        ecol[pos] = col[i];
    }
}

// transpose 2L weight matrices (64x64): wt[m][k][o] = w[m][o][k]
__global__ void transpose_kernel(const float* __restrict__ cw, const float* __restrict__ hw,
                                 float* __restrict__ wt, int L) {
    int idx = blockIdx.x * blockDim.x + threadIdx.x;
    int total = 2 * L * 4096;
    if (idx >= total) return;
    int mat = idx >> 12;
    int k = (idx >> 6) & 63;
    int o = idx & 63;
    const float* src = (mat < L) ? (cw + (size_t)mat * 4096) : (hw + (size_t)(mat - L) * 4096);
    wt[idx] = src[o * 64 + k];
}

// ---------------- layer kernels ----------------

// m[node] = relu(h[node] @ w^T), wt is w^T laid out [k][o]
__global__ __launch_bounds__(256, 2) void mm_relu_kernel(const float* __restrict__ h,
                                                         const float* __restrict__ wt,
                                                         float* __restrict__ out, int n) {
    int node = blockIdx.x * blockDim.x + threadIdx.x;
    if (node >= n) return;
    const float4* h4 = (const float4*)(h + (size_t)node * HIDDEN);
    float4 hv[16];
#pragma unroll
    for (int j = 0; j < 16; j++) hv[j] = h4[j];
    float acc[64];
#pragma unroll
    for (int o = 0; o < 64; o++) acc[o] = 0.f;
#pragma unroll
    for (int k4 = 0; k4 < 16; k4++) {
        float4 hk = hv[k4];
#pragma unroll
        for (int kk = 0; kk < 4; kk++) {
            float hs = (kk == 0) ? hk.x : (kk == 1) ? hk.y : (kk == 2) ? hk.z : hk.w;
            const float4* w4 = (const float4*)(wt + (size_t)(k4 * 4 + kk) * 64);
#pragma unroll
            for (int j = 0; j < 16; j++) {
                float4 wv = w4[j];
                acc[4 * j + 0] = fmaf(hs, wv.x, acc[4 * j + 0]);
                acc[4 * j + 1] = fmaf(hs, wv.y, acc[4 * j + 1]);
                acc[4 * j + 2] = fmaf(hs, wv.z, acc[4 * j + 2]);
                acc[4 * j + 3] = fmaf(hs, wv.w, acc[4 * j + 3]);
            }
        }
    }
    float4* o4 = (float4*)(out + (size_t)node * HIDDEN);
#pragma unroll
    for (int j = 0; j < 16; j++) {
        float4 v;
        v.x = fmaxf(acc[4 * j + 0], 0.f);
        v.y = fmaxf(acc[4 * j + 1], 0.f);
        v.z = fmaxf(acc[4 * j + 2], 0.f);
        v.w = fmaxf(acc[4 * j + 3], 0.f);
        o4[j] = v;
    }
}

// out[node] = rmsnorm(h[node] + sum_{e in CSR[node]} m[ecol[e]], nw)
// one wave per node, lane = channel; 4-way unrolled edge loop for MLP
__global__ __launch_bounds__(256) void aggregate_kernel(const float* __restrict__ h,
                                                        const float* __restrict__ m,
                                                        const int* __restrict__ row_ptr,
                                                        const int* __restrict__ ecol,
                                                        const float* __restrict__ nw,
                                                        float* __restrict__ out, int n) {
    int lane = threadIdx.x & 63;
    int node = (blockIdx.x * blockDim.x + threadIdx.x) >> 6;
    if (node >= n) return;
    int beg = row_ptr[node];
    int end = row_ptr[node + 1];
    float s0 = h[(size_t)node * HIDDEN + lane];
    float s1 = 0.f, s2 = 0.f, s3 = 0.f;
    int e = beg;
    for (; e + 4 <= end; e += 4) {
        int c0 = ecol[e + 0];
        int c1 = ecol[e + 1];
        int c2 = ecol[e + 2];
        int c3 = ecol[e + 3];
        float v0 = m[(size_t)c0 * HIDDEN + lane];
        float v1 = m[(size_t)c1 * HIDDEN + lane];
        float v2 = m[(size_t)c2 * HIDDEN + lane];
        float v3 = m[(size_t)c3 * HIDDEN + lane];
        s0 += v0; s1 += v1; s2 += v2; s3 += v3;
    }
    for (; e < end; e++) s0 += m[(size_t)ecol[e] * HIDDEN + lane];
    float s = (s0 + s1) + (s2 + s3);
    float ss = s * s;
#pragma unroll
    for (int off = 32; off > 0; off >>= 1) ss += __shfl_xor(ss, off, 64);
    float inv = rsqrtf(ss * (1.0f / 64.0f) + EPS);
    out[(size_t)node * HIDDEN + lane] = s * inv * nw[lane];
}

// h[node] = rmsnorm(h[node] + relu(h[node] @ w^T), nw)   (in place)
__global__ __launch_bounds__(256, 2) void hidden_kernel(float* __restrict__ h,
                                                        const float* __restrict__ wt,
                                                        const float* __restrict__ nw, int n) {
    int node = blockIdx.x * blockDim.x + threadIdx.x;
    if (node >= n) return;
    float4* h4 = (float4*)(h + (size_t)node * HIDDEN);
    float4 hv[16];
#pragma unroll
    for (int j = 0; j < 16; j++) hv[j] = h4[j];
    float acc[64];
#pragma unroll
    for (int o = 0; o < 64; o++) acc[o] = 0.f;
#pragma unroll
    for (int k4 = 0; k4 < 16; k4++) {
        float4 hk = hv[k4];
#pragma unroll
        for (int kk = 0; kk < 4; kk++) {
            float hs = (kk == 0) ? hk.x : (kk == 1) ? hk.y : (kk == 2) ? hk.z : hk.w;
            const float4* w4 = (const float4*)(wt + (size_t)(k4 * 4 + kk) * 64);
#pragma unroll
            for (int j = 0; j < 16; j++) {
                float4 wv = w4[j];
                acc[4 * j + 0] = fmaf(hs, wv.x, acc[4 * j + 0]);
                acc[4 * j + 1] = fmaf(hs, wv.y, acc[4 * j + 1]);
                acc[4 * j + 2] = fmaf(hs, wv.z, acc[4 * j + 2]);
                acc[4 * j + 3] = fmaf(hs, wv.w, acc[4 * j + 3]);
            }
        }
    }
    // s = h + relu(y); rmsnorm in registers
    float sumsq = 0.f;
#pragma unroll
    for (int j = 0; j < 16; j++) {
        float4 hk = hv[j];
        acc[4 * j + 0] = hk.x + fmaxf(acc[4 * j + 0], 0.f);
        acc[4 * j + 1] = hk.y + fmaxf(acc[4 * j + 1], 0.f);
        acc[4 * j + 2] = hk.z + fmaxf(acc[4 * j + 2], 0.f);
        acc[4 * j + 3] = hk.w + fmaxf(acc[4 * j + 3], 0.f);
        sumsq += acc[4 * j + 0] * acc[4 * j + 0];
        sumsq += acc[4 * j + 1] * acc[4 * j + 1];
        sumsq += acc[4 * j + 2] * acc[4 * j + 2];
        sumsq += acc[4 * j + 3] * acc[4 * j + 3];
    }
    float inv = rsqrtf(sumsq * (1.0f / 64.0f) + EPS);
#pragma unroll
    for (int j = 0; j < 16; j++) {
        float4 v;
        v.x = acc[4 * j + 0] * inv * nw[4 * j + 0];
        v.y = acc[4 * j + 1] * inv * nw[4 * j + 1];
        v.z = acc[4 * j + 2] * inv * nw[4 * j + 2];
        v.w = acc[4 * j + 3] * inv * nw[4 * j + 3];
        h4[j] = v;
    }
}

// ---------------- launch ----------------

static inline size_t align_up(size_t x, size_t a) { return (x + a - 1) & ~(a - 1); }

extern "C" void kernel_launch(void* const* d_in, const int* in_sizes, int n_in,
                              void* d_out, int out_size, void* d_ws, size_t ws_size,
                              hipStream_t stream) {
    const float* x       = (const float*)d_in[0];
    const float* conv_w  = (const float*)d_in[1];
    const float* conv_nw = (const float*)d_in[2];
    const float* hid_w   = (const float*)d_in[3];
    const float* hid_nw  = (const float*)d_in[4];
    const int*   row     = (const int*)d_in[5];
    const int*   col     = (const int*)d_in[6];
    float* out = (float*)d_out;

    const int n = in_sizes[0] / HIDDEN;   // 100000
    const int e = in_sizes[5];            // 800000
    const int L = in_sizes[1] / 4096;     // 4

    // workspace layout
    size_t off = 0;
    char* ws = (char*)d_ws;
    float* wt = (float*)(ws + off);      off = align_up(off + (size_t)2 * L * 4096 * 4, 16);
    float* m = (float*)(ws + off);       off = align_up(off + (size_t)n * HIDDEN * 4, 16);
    int* row_ptr = (int*)(ws + off);     off = align_up(off + (size_t)(n + 1) * 4, 16);
    int* cnt = (int*)(ws + off);         off = align_up(off + (size_t)n * 4, 16);
    int* bsum = (int*)(ws + off);        off = align_up(off + (size_t)1024 * 4, 16);
    int* ecol = (int*)(ws + off);        off = align_up(off + (size_t)e * 4, 16);

    const int nb = (n + 255) / 256;       // 391 scan blocks

    // CSR build (edges constant across layers -> build once per launch)
    hipMemsetAsync(cnt, 0, (size_t)n * 4, stream);
    hist_kernel<<<(e + 255) / 256, 256, 0, stream>>>(row, cnt, e);
    block_sum_kernel<<<nb, 256, 0, stream>>>(cnt, bsum, n);
    scan_bsum_kernel<<<1, 1024, 0, stream>>>(bsum, nb, row_ptr + n);  // total -> row_ptr[n]
    scan_final_kernel<<<nb, 256, 0, stream>>>(cnt, bsum, row_ptr, n);
    hipMemsetAsync(cnt, 0, (size_t)n * 4, stream);
    fill_kernel<<<(e + 255) / 256, 256, 0, stream>>>(row, col, row_ptr, cnt, ecol, e);

    // pre-transpose weights to [k][o]
    transpose_kernel<<<(2 * L * 4096 + 255) / 256, 256, 0, stream>>>(conv_w, hid_w, wt, L);

    const int mm_blocks = (n + 255) / 256;
    const int agg_blocks = (n * 64 + 255) / 256;   // one wave per node
    const float* hin = x;
    for (int l = 0; l < L; l++) {
        mm_relu_kernel<<<mm_blocks, 256, 0, stream>>>(hin, wt + (size_t)l * 4096, m, n);
        aggregate_kernel<<<agg_blocks, 256, 0, stream>>>(hin, m, row_ptr, ecol,
                                                         conv_nw + (size_t)l * HIDDEN, out, n);
        hidden_kernel<<<mm_blocks, 256, 0, stream>>>(out, wt + (size_t)(L + l) * 4096,
                                                     hid_nw + (size_t)l * HIDDEN, n);
        hin = out;
    }
}

// Round 3
// 516.905 us; speedup vs baseline: 2.1321x; 1.2956x over previous
//
#include <hip/hip_runtime.h>
#include <hip/hip_bf16.h>

#define HIDDEN 64
#define EPS 1e-5f
#define NPB 64            // nodes per block in GEMM kernels
#define HPAD 68           // padded LDS row stride (floats): 272B, 16B-aligned, conflict-free

// ---------------- CSR build ----------------

__global__ void hist_kernel(const int* __restrict__ row, int* __restrict__ cnt, int e) {
    int i = blockIdx.x * blockDim.x + threadIdx.x;
    if (i < e) atomicAdd(&cnt[row[i]], 1);
}

// per-block sums: bsum[b] = sum(cnt[b*256 .. b*256+255])
__global__ __launch_bounds__(256) void block_sum_kernel(const int* __restrict__ cnt,
                                                        int* __restrict__ bsum, int n) {
    __shared__ int wsum[4];
    int tid = threadIdx.x;
    int i = blockIdx.x * 256 + tid;
    int v = (i < n) ? cnt[i] : 0;
#pragma unroll
    for (int off = 32; off > 0; off >>= 1) v += __shfl_xor(v, off, 64);
    if ((tid & 63) == 0) wsum[tid >> 6] = v;
    __syncthreads();
    if (tid == 0) bsum[blockIdx.x] = wsum[0] + wsum[1] + wsum[2] + wsum[3];
}

// single block: exclusive scan of bsum[0..nb), total -> *total_out
__global__ __launch_bounds__(1024) void scan_bsum_kernel(int* __restrict__ bsum, int nb,
                                                         int* __restrict__ total_out) {
    __shared__ int wsum[16];
    __shared__ int wexcl[16];
    int tid = threadIdx.x;
    int lane = tid & 63;
    int w = tid >> 6;
    int v = (tid < nb) ? bsum[tid] : 0;
    int sc = v;
#pragma unroll
    for (int off = 1; off < 64; off <<= 1) {
        int t = __shfl_up(sc, off, 64);
        if (lane >= off) sc += t;
    }
    if (lane == 63) wsum[w] = sc;
    __syncthreads();
    if (tid == 0) {
        int a = 0;
#pragma unroll
        for (int j = 0; j < 16; j++) { wexcl[j] = a; a += wsum[j]; }
        *total_out = a;
    }
    __syncthreads();
    if (tid < nb) bsum[tid] = wexcl[w] + (sc - v);
}

// per-block scan + add block offset -> row_ptr
__global__ __launch_bounds__(256) void scan_final_kernel(const int* __restrict__ cnt,
                                                         const int* __restrict__ bexcl,
                                                         int* __restrict__ row_ptr, int n) {
    __shared__ int wsum[4];
    __shared__ int wexcl[4];
    int tid = threadIdx.x;
    int lane = tid & 63;
    int w = tid >> 6;
    int i = blockIdx.x * 256 + tid;
    int v = (i < n) ? cnt[i] : 0;
    int sc = v;
#pragma unroll
    for (int off = 1; off < 64; off <<= 1) {
        int t = __shfl_up(sc, off, 64);
        if (lane >= off) sc += t;
    }
    if (lane == 63) wsum[w] = sc;
    __syncthreads();
    if (tid == 0) {
        int a = 0;
#pragma unroll
        for (int j = 0; j < 4; j++) { wexcl[j] = a; a += wsum[j]; }
    }
    __syncthreads();
    if (i < n) row_ptr[i] = bexcl[blockIdx.x] + wexcl[w] + (sc - v);
}

__global__ void fill_kernel(const int* __restrict__ row, const int* __restrict__ col,
                            const int* __restrict__ row_ptr, int* __restrict__ cnt,
                            int* __restrict__ ecol, int e) {
    int i = blockIdx.x * blockDim.x + threadIdx.x;
    if (i < e) {
        int r = row[i];
        int pos = row_ptr[r] + atomicAdd(&cnt[r], 1);
        ecol[pos] = col[i];
    }
}

// transpose 2L weight matrices (64x64): wt[m][k][o] = w[m][o][k]
__global__ void transpose_kernel(const float* __restrict__ cw, const float* __restrict__ hw,
                                 float* __restrict__ wt, int L) {
    int idx = blockIdx.x * blockDim.x + threadIdx.x;
    int total = 2 * L * 4096;
    if (idx >= total) return;
    int mat = idx >> 12;
    int k = (idx >> 6) & 63;
    int o = idx & 63;
    const float* src = (mat < L) ? (cw + (size_t)mat * 4096) : (hw + (size_t)(mat - L) * 4096);
    wt[idx] = src[o * 64 + k];
}

// ---------------- GEMM layer kernels (LDS-tiled) ----------------
// Block: 256 threads, NPB=64 nodes. Thread t: local nodes n0=t>>3, n1=n0+32,
// outputs o = (t&7)*8 .. +7. LDS: weights 16KB + h tile (stride HPAD) 17.4KB.
// Bank analysis: wt b128 reads 2-way (free); s_h b32 reads conflict-free
// (bank = (4*n0 + k) % 32, n0 spans 0..7 per wave).

__device__ __forceinline__ void stage_tiles(const float* __restrict__ h,
                                            const float* __restrict__ wt,
                                            float* s_wt, float* s_h,
                                            int base, int n, int tid) {
    const float4* w4 = (const float4*)wt;
    float4* sw4 = (float4*)s_wt;
#pragma unroll
    for (int i = tid; i < 1024; i += 256) sw4[i] = w4[i];
#pragma unroll
    for (int i = tid; i < NPB * 16; i += 256) {
        int node = i >> 4;
        int j = i & 15;
        float4 v = make_float4(0.f, 0.f, 0.f, 0.f);
        if (base + node < n) v = ((const float4*)(h + (size_t)(base + node) * HIDDEN))[j];
        *(float4*)(&s_h[node * HPAD + j * 4]) = v;
    }
}

#define GEMM_KLOOP(ACC0, ACC1)                                                 \
    _Pragma("unroll 4")                                                        \
    for (int k = 0; k < 64; k++) {                                             \
        float4 wa = *(const float4*)(&s_wt[k * 64 + og]);                      \
        float4 wb = *(const float4*)(&s_wt[k * 64 + og + 4]);                  \
        float a = h0p[k];                                                      \
        float b = h1p[k];                                                      \
        ACC0[0] = fmaf(a, wa.x, ACC0[0]); ACC1[0] = fmaf(b, wa.x, ACC1[0]);    \
        ACC0[1] = fmaf(a, wa.y, ACC0[1]); ACC1[1] = fmaf(b, wa.y, ACC1[1]);    \
        ACC0[2] = fmaf(a, wa.z, ACC0[2]); ACC1[2] = fmaf(b, wa.z, ACC1[2]);    \
        ACC0[3] = fmaf(a, wa.w, ACC0[3]); ACC1[3] = fmaf(b, wa.w, ACC1[3]);    \
        ACC0[4] = fmaf(a, wb.x, ACC0[4]); ACC1[4] = fmaf(b, wb.x, ACC1[4]);    \
        ACC0[5] = fmaf(a, wb.y, ACC0[5]); ACC1[5] = fmaf(b, wb.y, ACC1[5]);    \
        ACC0[6] = fmaf(a, wb.z, ACC0[6]); ACC1[6] = fmaf(b, wb.z, ACC1[6]);    \
        ACC0[7] = fmaf(a, wb.w, ACC0[7]); ACC1[7] = fmaf(b, wb.w, ACC1[7]);    \
    }

// m[node] = relu(h[node] @ w^T)
__global__ __launch_bounds__(256) void mm_relu_kernel(const float* __restrict__ h,
                                                      const float* __restrict__ wt,
                                                      float* __restrict__ m, int n) {
    __shared__ float s_wt[64 * 64];
    __shared__ float s_h[NPB * HPAD];
    int tid = threadIdx.x;
    int base = blockIdx.x * NPB;
    stage_tiles(h, wt, s_wt, s_h, base, n, tid);
    __syncthreads();
    int og = (tid & 7) * 8;
    int n0 = tid >> 3;
    int n1 = n0 + 32;
    const float* h0p = &s_h[n0 * HPAD];
    const float* h1p = &s_h[n1 * HPAD];
    float acc0[8], acc1[8];
#pragma unroll
    for (int j = 0; j < 8; j++) { acc0[j] = 0.f; acc1[j] = 0.f; }
    GEMM_KLOOP(acc0, acc1)
    if (base + n0 < n) {
        float4 v0 = make_float4(fmaxf(acc0[0], 0.f), fmaxf(acc0[1], 0.f),
                                fmaxf(acc0[2], 0.f), fmaxf(acc0[3], 0.f));
        float4 v1 = make_float4(fmaxf(acc0[4], 0.f), fmaxf(acc0[5], 0.f),
                                fmaxf(acc0[6], 0.f), fmaxf(acc0[7], 0.f));
        float4* o4 = (float4*)(m + (size_t)(base + n0) * HIDDEN + og);
        o4[0] = v0; o4[1] = v1;
    }
    if (base + n1 < n) {
        float4 v0 = make_float4(fmaxf(acc1[0], 0.f), fmaxf(acc1[1], 0.f),
                                fmaxf(acc1[2], 0.f), fmaxf(acc1[3], 0.f));
        float4 v1 = make_float4(fmaxf(acc1[4], 0.f), fmaxf(acc1[5], 0.f),
                                fmaxf(acc1[6], 0.f), fmaxf(acc1[7], 0.f));
        float4* o4 = (float4*)(m + (size_t)(base + n1) * HIDDEN + og);
        o4[0] = v0; o4[1] = v1;
    }
}

// h[node] = rmsnorm(h[node] + relu(h[node] @ w^T), nw)  (in place; block reads only own rows)
__global__ __launch_bounds__(256) void hidden_kernel(float* __restrict__ h,
                                                     const float* __restrict__ wt,
                                                     const float* __restrict__ nw, int n) {
    __shared__ float s_wt[64 * 64];
    __shared__ float s_h[NPB * HPAD];
    int tid = threadIdx.x;
    int base = blockIdx.x * NPB;
    stage_tiles(h, wt, s_wt, s_h, base, n, tid);
    __syncthreads();
    int og = (tid & 7) * 8;
    int n0 = tid >> 3;
    int n1 = n0 + 32;
    const float* h0p = &s_h[n0 * HPAD];
    const float* h1p = &s_h[n1 * HPAD];
    float acc0[8], acc1[8];
#pragma unroll
    for (int j = 0; j < 8; j++) { acc0[j] = 0.f; acc1[j] = 0.f; }
    GEMM_KLOOP(acc0, acc1)
    // residual + relu; partial sumsq over this thread's 8 outputs per node
    float ssq0 = 0.f, ssq1 = 0.f;
#pragma unroll
    for (int j = 0; j < 8; j++) {
        acc0[j] = h0p[og + j] + fmaxf(acc0[j], 0.f);
        acc1[j] = h1p[og + j] + fmaxf(acc1[j], 0.f);
        ssq0 += acc0[j] * acc0[j];
        ssq1 += acc1[j] * acc1[j];
    }
    // reduce across the 8 threads of each node group (lanes 8-aligned)
#pragma unroll
    for (int off = 1; off < 8; off <<= 1) {
        ssq0 += __shfl_xor(ssq0, off, 64);
        ssq1 += __shfl_xor(ssq1, off, 64);
    }
    float inv0 = rsqrtf(ssq0 * (1.0f / 64.0f) + EPS);
    float inv1 = rsqrtf(ssq1 * (1.0f / 64.0f) + EPS);
    float w0 = nw[og + 0], w1 = nw[og + 1], w2 = nw[og + 2], w3 = nw[og + 3];
    float w4 = nw[og + 4], w5 = nw[og + 5], w6 = nw[og + 6], w7 = nw[og + 7];
    if (base + n0 < n) {
        float4 v0 = make_float4(acc0[0] * inv0 * w0, acc0[1] * inv0 * w1,
                                acc0[2] * inv0 * w2, acc0[3] * inv0 * w3);
        float4 v1 = make_float4(acc0[4] * inv0 * w4, acc0[5] * inv0 * w5,
                                acc0[6] * inv0 * w6, acc0[7] * inv0 * w7);
        float4* o4 = (float4*)(h + (size_t)(base + n0) * HIDDEN + og);
        o4[0] = v0; o4[1] = v1;
    }
    if (base + n1 < n) {
        float4 v0 = make_float4(acc1[0] * inv1 * w0, acc1[1] * inv1 * w1,
                                acc1[2] * inv1 * w2, acc1[3] * inv1 * w3);
        float4 v1 = make_float4(acc1[4] * inv1 * w4, acc1[5] * inv1 * w5,
                                acc1[6] * inv1 * w6, acc1[7] * inv1 * w7);
        float4* o4 = (float4*)(h + (size_t)(base + n1) * HIDDEN + og);
        o4[0] = v0; o4[1] = v1;
    }
}

// ---------------- aggregation ----------------

// out[node] = rmsnorm(h[node] + sum_{e in CSR[node]} m[ecol[e]], nw)
// one wave per node, lane = channel; 4-way unrolled edge loop for MLP
__global__ __launch_bounds__(256) void aggregate_kernel(const float* __restrict__ h,
                                                        const float* __restrict__ m,
                                                        const int* __restrict__ row_ptr,
                                                        const int* __restrict__ ecol,
                                                        const float* __restrict__ nw,
                                                        float* __restrict__ out, int n) {
    int lane = threadIdx.x & 63;
    int node = (blockIdx.x * blockDim.x + threadIdx.x) >> 6;
    if (node >= n) return;
    int beg = row_ptr[node];
    int end = row_ptr[node + 1];
    float s0 = h[(size_t)node * HIDDEN + lane];
    float s1 = 0.f, s2 = 0.f, s3 = 0.f;
    int e = beg;
    for (; e + 4 <= end; e += 4) {
        int c0 = ecol[e + 0];
        int c1 = ecol[e + 1];
        int c2 = ecol[e + 2];
        int c3 = ecol[e + 3];
        float v0 = m[(size_t)c0 * HIDDEN + lane];
        float v1 = m[(size_t)c1 * HIDDEN + lane];
        float v2 = m[(size_t)c2 * HIDDEN + lane];
        float v3 = m[(size_t)c3 * HIDDEN + lane];
        s0 += v0; s1 += v1; s2 += v2; s3 += v3;
    }
    for (; e < end; e++) s0 += m[(size_t)ecol[e] * HIDDEN + lane];
    float s = (s0 + s1) + (s2 + s3);
    float ss = s * s;
#pragma unroll
    for (int off = 32; off > 0; off >>= 1) ss += __shfl_xor(ss, off, 64);
    float inv = rsqrtf(ss * (1.0f / 64.0f) + EPS);
    out[(size_t)node * HIDDEN + lane] = s * inv * nw[lane];
}

// ---------------- launch ----------------

static inline size_t align_up(size_t x, size_t a) { return (x + a - 1) & ~(a - 1); }

extern "C" void kernel_launch(void* const* d_in, const int* in_sizes, int n_in,
                              void* d_out, int out_size, void* d_ws, size_t ws_size,
                              hipStream_t stream) {
    const float* x       = (const float*)d_in[0];
    const float* conv_w  = (const float*)d_in[1];
    const float* conv_nw = (const float*)d_in[2];
    const float* hid_w   = (const float*)d_in[3];
    const float* hid_nw  = (const float*)d_in[4];
    const int*   row     = (const int*)d_in[5];
    const int*   col     = (const int*)d_in[6];
    float* out = (float*)d_out;

    const int n = in_sizes[0] / HIDDEN;   // 100000
    const int e = in_sizes[5];            // 800000
    const int L = in_sizes[1] / 4096;     // 4

    // workspace layout
    size_t off = 0;
    char* ws = (char*)d_ws;
    float* wt = (float*)(ws + off);      off = align_up(off + (size_t)2 * L * 4096 * 4, 16);
    float* m = (float*)(ws + off);       off = align_up(off + (size_t)n * HIDDEN * 4, 16);
    int* row_ptr = (int*)(ws + off);     off = align_up(off + (size_t)(n + 1) * 4, 16);
    int* cnt = (int*)(ws + off);         off = align_up(off + (size_t)n * 4, 16);
    int* bsum = (int*)(ws + off);        off = align_up(off + (size_t)1024 * 4, 16);
    int* ecol = (int*)(ws + off);        off = align_up(off + (size_t)e * 4, 16);

    const int nb = (n + 255) / 256;       // scan blocks

    // CSR build (edges constant across layers -> build once per launch)
    hipMemsetAsync(cnt, 0, (size_t)n * 4, stream);
    hist_kernel<<<(e + 255) / 256, 256, 0, stream>>>(row, cnt, e);
    block_sum_kernel<<<nb, 256, 0, stream>>>(cnt, bsum, n);
    scan_bsum_kernel<<<1, 1024, 0, stream>>>(bsum, nb, row_ptr + n);  // total -> row_ptr[n]
    scan_final_kernel<<<nb, 256, 0, stream>>>(cnt, bsum, row_ptr, n);
    hipMemsetAsync(cnt, 0, (size_t)n * 4, stream);
    fill_kernel<<<(e + 255) / 256, 256, 0, stream>>>(row, col, row_ptr, cnt, ecol, e);

    // pre-transpose weights to [k][o]
    transpose_kernel<<<(2 * L * 4096 + 255) / 256, 256, 0, stream>>>(conv_w, hid_w, wt, L);

    const int gemm_blocks = (n + NPB - 1) / NPB;
    const int agg_blocks = (n * 64 + 255) / 256;   // one wave per node
    const float* hin = x;
    for (int l = 0; l < L; l++) {
        mm_relu_kernel<<<gemm_blocks, 256, 0, stream>>>(hin, wt + (size_t)l * 4096, m, n);
        aggregate_kernel<<<agg_blocks, 256, 0, stream>>>(hin, m, row_ptr, ecol,
                                                         conv_nw + (size_t)l * HIDDEN, out, n);
        hidden_kernel<<<gemm_blocks, 256, 0, stream>>>(out, wt + (size_t)(L + l) * 4096,
                                                       hid_nw + (size_t)l * HIDDEN, n);
        hin = out;
    }
}

// Round 4
// 468.862 us; speedup vs baseline: 2.3506x; 1.1025x over previous
//
#include <hip/hip_runtime.h>
#include <hip/hip_bf16.h>

#define HIDDEN 64
#define EPS 1e-5f
#define NPB 64            // nodes per block in GEMM kernels
#define HPAD 68           // padded LDS row stride (floats)
#define FPASS 8           // fill passes (row-range write localization)

// ---------------- CSR build ----------------

__global__ void hist_kernel(const int* __restrict__ row, int* __restrict__ cnt, int e) {
    int i = blockIdx.x * blockDim.x + threadIdx.x;
    if (i < e) atomicAdd(&cnt[row[i]], 1);
}

// per-block sums: bsum[b] = sum(cnt[b*256 .. b*256+255])
__global__ __launch_bounds__(256) void block_sum_kernel(const int* __restrict__ cnt,
                                                        int* __restrict__ bsum, int n) {
    __shared__ int wsum[4];
    int tid = threadIdx.x;
    int i = blockIdx.x * 256 + tid;
    int v = (i < n) ? cnt[i] : 0;
#pragma unroll
    for (int off = 32; off > 0; off >>= 1) v += __shfl_xor(v, off, 64);
    if ((tid & 63) == 0) wsum[tid >> 6] = v;
    __syncthreads();
    if (tid == 0) bsum[blockIdx.x] = wsum[0] + wsum[1] + wsum[2] + wsum[3];
}

// single block: exclusive scan of bsum[0..nb), total -> *total_out
__global__ __launch_bounds__(1024) void scan_bsum_kernel(int* __restrict__ bsum, int nb,
                                                         int* __restrict__ total_out) {
    __shared__ int wsum[16];
    __shared__ int wexcl[16];
    int tid = threadIdx.x;
    int lane = tid & 63;
    int w = tid >> 6;
    int v = (tid < nb) ? bsum[tid] : 0;
    int sc = v;
#pragma unroll
    for (int off = 1; off < 64; off <<= 1) {
        int t = __shfl_up(sc, off, 64);
        if (lane >= off) sc += t;
    }
    if (lane == 63) wsum[w] = sc;
    __syncthreads();
    if (tid == 0) {
        int a = 0;
#pragma unroll
        for (int j = 0; j < 16; j++) { wexcl[j] = a; a += wsum[j]; }
        *total_out = a;
    }
    __syncthreads();
    if (tid < nb) bsum[tid] = wexcl[w] + (sc - v);
}

// per-block scan + add block offset -> row_ptr
__global__ __launch_bounds__(256) void scan_final_kernel(const int* __restrict__ cnt,
                                                         const int* __restrict__ bexcl,
                                                         int* __restrict__ row_ptr, int n) {
    __shared__ int wsum[4];
    __shared__ int wexcl[4];
    int tid = threadIdx.x;
    int lane = tid & 63;
    int w = tid >> 6;
    int i = blockIdx.x * 256 + tid;
    int v = (i < n) ? cnt[i] : 0;
    int sc = v;
#pragma unroll
    for (int off = 1; off < 64; off <<= 1) {
        int t = __shfl_up(sc, off, 64);
        if (lane >= off) sc += t;
    }
    if (lane == 63) wsum[w] = sc;
    __syncthreads();
    if (tid == 0) {
        int a = 0;
#pragma unroll
        for (int j = 0; j < 4; j++) { wexcl[j] = a; a += wsum[j]; }
    }
    __syncthreads();
    if (i < n) row_ptr[i] = bexcl[blockIdx.x] + wexcl[w] + (sc - v);
}

// multi-pass fill: pass p handles rows in [n*p/FPASS, n*(p+1)/FPASS) so ecol
// writes stay within a 400KB window -> L2 lines fill completely before
// writeback (was 16x write amplification as a single-pass random scatter).
__global__ __launch_bounds__(256) void fill_kernel(const int* __restrict__ row,
                                                   const int* __restrict__ col,
                                                   const int* __restrict__ row_ptr,
                                                   int* __restrict__ cnt,
                                                   int* __restrict__ ecol, int e, int n) {
    int tid0 = blockIdx.x * blockDim.x + threadIdx.x;
    int stride = gridDim.x * blockDim.x;
    for (int p = 0; p < FPASS; p++) {
        int lo = (int)(((long long)n * p) / FPASS);
        int hi = (int)(((long long)n * (p + 1)) / FPASS);
        for (int i = tid0; i < e; i += stride) {
            int r = row[i];
            if (r >= lo && r < hi) {
                int pos = row_ptr[r] + atomicAdd(&cnt[r], 1);
                ecol[pos] = col[i];
            }
        }
    }
}

// transpose 2L weight matrices (64x64): wt[m][k][o] = w[m][o][k]
__global__ void transpose_kernel(const float* __restrict__ cw, const float* __restrict__ hw,
                                 float* __restrict__ wt, int L) {
    int idx = blockIdx.x * blockDim.x + threadIdx.x;
    int total = 2 * L * 4096;
    if (idx >= total) return;
    int mat = idx >> 12;
    int k = (idx >> 6) & 63;
    int o = idx & 63;
    const float* src = (mat < L) ? (cw + (size_t)mat * 4096) : (hw + (size_t)(mat - L) * 4096);
    wt[idx] = src[o * 64 + k];
}

// ---------------- GEMM layer kernels (LDS-tiled) ----------------

__device__ __forceinline__ void stage_tiles(const float* __restrict__ h,
                                            const float* __restrict__ wt,
                                            float* s_wt, float* s_h,
                                            int base, int n, int tid) {
    const float4* w4 = (const float4*)wt;
    float4* sw4 = (float4*)s_wt;
#pragma unroll
    for (int i = tid; i < 1024; i += 256) sw4[i] = w4[i];
#pragma unroll
    for (int i = tid; i < NPB * 16; i += 256) {
        int node = i >> 4;
        int j = i & 15;
        float4 v = make_float4(0.f, 0.f, 0.f, 0.f);
        if (base + node < n) v = ((const float4*)(h + (size_t)(base + node) * HIDDEN))[j];
        *(float4*)(&s_h[node * HPAD + j * 4]) = v;
    }
}

#define GEMM_KLOOP(ACC0, ACC1)                                                 \
    _Pragma("unroll 4")                                                        \
    for (int k = 0; k < 64; k++) {                                             \
        float4 wa = *(const float4*)(&s_wt[k * 64 + og]);                      \
        float4 wb = *(const float4*)(&s_wt[k * 64 + og + 4]);                  \
        float a = h0p[k];                                                      \
        float b = h1p[k];                                                      \
        ACC0[0] = fmaf(a, wa.x, ACC0[0]); ACC1[0] = fmaf(b, wa.x, ACC1[0]);    \
        ACC0[1] = fmaf(a, wa.y, ACC0[1]); ACC1[1] = fmaf(b, wa.y, ACC1[1]);    \
        ACC0[2] = fmaf(a, wa.z, ACC0[2]); ACC1[2] = fmaf(b, wa.z, ACC1[2]);    \
        ACC0[3] = fmaf(a, wa.w, ACC0[3]); ACC1[3] = fmaf(b, wa.w, ACC1[3]);    \
        ACC0[4] = fmaf(a, wb.x, ACC0[4]); ACC1[4] = fmaf(b, wb.x, ACC1[4]);    \
        ACC0[5] = fmaf(a, wb.y, ACC0[5]); ACC1[5] = fmaf(b, wb.y, ACC1[5]);    \
        ACC0[6] = fmaf(a, wb.z, ACC0[6]); ACC1[6] = fmaf(b, wb.z, ACC1[6]);    \
        ACC0[7] = fmaf(a, wb.w, ACC0[7]); ACC1[7] = fmaf(b, wb.w, ACC1[7]);    \
    }

__device__ __forceinline__ unsigned int pack_bf16x2(float a, float b) {
    __hip_bfloat16 ba = __float2bfloat16(a);
    __hip_bfloat16 bb = __float2bfloat16(b);
    unsigned short ua = *(unsigned short*)&ba;
    unsigned short ub = *(unsigned short*)&bb;
    return (unsigned int)ua | ((unsigned int)ub << 16);
}

// m[node] = bf16(relu(h[node] @ w^T))
__global__ __launch_bounds__(256) void mm_relu_kernel(const float* __restrict__ h,
                                                      const float* __restrict__ wt,
                                                      __hip_bfloat16* __restrict__ m, int n) {
    __shared__ float s_wt[64 * 64];
    __shared__ float s_h[NPB * HPAD];
    int tid = threadIdx.x;
    int base = blockIdx.x * NPB;
    stage_tiles(h, wt, s_wt, s_h, base, n, tid);
    __syncthreads();
    int og = (tid & 7) * 8;
    int n0 = tid >> 3;
    int n1 = n0 + 32;
    const float* h0p = &s_h[n0 * HPAD];
    const float* h1p = &s_h[n1 * HPAD];
    float acc0[8], acc1[8];
#pragma unroll
    for (int j = 0; j < 8; j++) { acc0[j] = 0.f; acc1[j] = 0.f; }
    GEMM_KLOOP(acc0, acc1)
    if (base + n0 < n) {
        uint4 v;
        v.x = pack_bf16x2(fmaxf(acc0[0], 0.f), fmaxf(acc0[1], 0.f));
        v.y = pack_bf16x2(fmaxf(acc0[2], 0.f), fmaxf(acc0[3], 0.f));
        v.z = pack_bf16x2(fmaxf(acc0[4], 0.f), fmaxf(acc0[5], 0.f));
        v.w = pack_bf16x2(fmaxf(acc0[6], 0.f), fmaxf(acc0[7], 0.f));
        *(uint4*)(m + (size_t)(base + n0) * HIDDEN + og) = v;
    }
    if (base + n1 < n) {
        uint4 v;
        v.x = pack_bf16x2(fmaxf(acc1[0], 0.f), fmaxf(acc1[1], 0.f));
        v.y = pack_bf16x2(fmaxf(acc1[2], 0.f), fmaxf(acc1[3], 0.f));
        v.z = pack_bf16x2(fmaxf(acc1[4], 0.f), fmaxf(acc1[5], 0.f));
        v.w = pack_bf16x2(fmaxf(acc1[6], 0.f), fmaxf(acc1[7], 0.f));
        *(uint4*)(m + (size_t)(base + n1) * HIDDEN + og) = v;
    }
}

// h[node] = rmsnorm(h[node] + relu(h[node] @ w^T), nw)  (in place)
__global__ __launch_bounds__(256) void hidden_kernel(float* __restrict__ h,
                                                     const float* __restrict__ wt,
                                                     const float* __restrict__ nw, int n) {
    __shared__ float s_wt[64 * 64];
    __shared__ float s_h[NPB * HPAD];
    int tid = threadIdx.x;
    int base = blockIdx.x * NPB;
    stage_tiles(h, wt, s_wt, s_h, base, n, tid);
    __syncthreads();
    int og = (tid & 7) * 8;
    int n0 = tid >> 3;
    int n1 = n0 + 32;
    const float* h0p = &s_h[n0 * HPAD];
    const float* h1p = &s_h[n1 * HPAD];
    float acc0[8], acc1[8];
#pragma unroll
    for (int j = 0; j < 8; j++) { acc0[j] = 0.f; acc1[j] = 0.f; }
    GEMM_KLOOP(acc0, acc1)
    float ssq0 = 0.f, ssq1 = 0.f;
#pragma unroll
    for (int j = 0; j < 8; j++) {
        acc0[j] = h0p[og + j] + fmaxf(acc0[j], 0.f);
        acc1[j] = h1p[og + j] + fmaxf(acc1[j], 0.f);
        ssq0 += acc0[j] * acc0[j];
        ssq1 += acc1[j] * acc1[j];
    }
#pragma unroll
    for (int off = 1; off < 8; off <<= 1) {
        ssq0 += __shfl_xor(ssq0, off, 64);
        ssq1 += __shfl_xor(ssq1, off, 64);
    }
    float inv0 = rsqrtf(ssq0 * (1.0f / 64.0f) + EPS);
    float inv1 = rsqrtf(ssq1 * (1.0f / 64.0f) + EPS);
    float w0 = nw[og + 0], w1 = nw[og + 1], w2 = nw[og + 2], w3 = nw[og + 3];
    float w4 = nw[og + 4], w5 = nw[og + 5], w6 = nw[og + 6], w7 = nw[og + 7];
    if (base + n0 < n) {
        float4 v0 = make_float4(acc0[0] * inv0 * w0, acc0[1] * inv0 * w1,
                                acc0[2] * inv0 * w2, acc0[3] * inv0 * w3);
        float4 v1 = make_float4(acc0[4] * inv0 * w4, acc0[5] * inv0 * w5,
                                acc0[6] * inv0 * w6, acc0[7] * inv0 * w7);
        float4* o4 = (float4*)(h + (size_t)(base + n0) * HIDDEN + og);
        o4[0] = v0; o4[1] = v1;
    }
    if (base + n1 < n) {
        float4 v0 = make_float4(acc1[0] * inv1 * w0, acc1[1] * inv1 * w1,
                                acc1[2] * inv1 * w2, acc1[3] * inv1 * w3);
        float4 v1 = make_float4(acc1[4] * inv1 * w4, acc1[5] * inv1 * w5,
                                acc1[6] * inv1 * w6, acc1[7] * inv1 * w7);
        float4* o4 = (float4*)(h + (size_t)(base + n1) * HIDDEN + og);
        o4[0] = v0; o4[1] = v1;
    }
}

// ---------------- aggregation ----------------

// out[node] = rmsnorm(h[node] + sum_{e in CSR[node]} bf16 m[ecol[e]], nw)
// one wave per node, lane = channel; 8 unconditional gathers in flight
__global__ __launch_bounds__(256) void aggregate_kernel(const float* __restrict__ h,
                                                        const __hip_bfloat16* __restrict__ m,
                                                        const int* __restrict__ row_ptr,
                                                        const int* __restrict__ ecol,
                                                        const float* __restrict__ nw,
                                                        float* __restrict__ out, int n) {
    int lane = threadIdx.x & 63;
    int node = (blockIdx.x * blockDim.x + threadIdx.x) >> 6;
    if (node >= n) return;
    int beg = row_ptr[node];
    int end = row_ptr[node + 1];
    float hval = h[(size_t)node * HIDDEN + lane];
    float acc[8];
#pragma unroll
    for (int j = 0; j < 8; j++) acc[j] = 0.f;
    for (int base = beg; base < end; base += 8) {
        int c[8];
#pragma unroll
        for (int j = 0; j < 8; j++) {
            int idx = base + j;
            c[j] = ecol[idx < end ? idx : end - 1];
        }
        float v[8];
#pragma unroll
        for (int j = 0; j < 8; j++)
            v[j] = __bfloat162float(m[(size_t)c[j] * HIDDEN + lane]);
#pragma unroll
        for (int j = 0; j < 8; j++)
            acc[j] += (base + j < end) ? v[j] : 0.f;
    }
    float s = hval + (((acc[0] + acc[1]) + (acc[2] + acc[3])) +
                      ((acc[4] + acc[5]) + (acc[6] + acc[7])));
    float ss = s * s;
#pragma unroll
    for (int off = 32; off > 0; off >>= 1) ss += __shfl_xor(ss, off, 64);
    float inv = rsqrtf(ss * (1.0f / 64.0f) + EPS);
    out[(size_t)node * HIDDEN + lane] = s * inv * nw[lane];
}

// ---------------- launch ----------------

static inline size_t align_up(size_t x, size_t a) { return (x + a - 1) & ~(a - 1); }

extern "C" void kernel_launch(void* const* d_in, const int* in_sizes, int n_in,
                              void* d_out, int out_size, void* d_ws, size_t ws_size,
                              hipStream_t stream) {
    const float* x       = (const float*)d_in[0];
    const float* conv_w  = (const float*)d_in[1];
    const float* conv_nw = (const float*)d_in[2];
    const float* hid_w   = (const float*)d_in[3];
    const float* hid_nw  = (const float*)d_in[4];
    const int*   row     = (const int*)d_in[5];
    const int*   col     = (const int*)d_in[6];
    float* out = (float*)d_out;

    const int n = in_sizes[0] / HIDDEN;   // 100000
    const int e = in_sizes[5];            // 800000
    const int L = in_sizes[1] / 4096;     // 4

    // workspace layout
    size_t off = 0;
    char* ws = (char*)d_ws;
    float* wt = (float*)(ws + off);            off = align_up(off + (size_t)2 * L * 4096 * 4, 16);
    __hip_bfloat16* m = (__hip_bfloat16*)(ws + off); off = align_up(off + (size_t)n * HIDDEN * 2, 16);
    int* row_ptr = (int*)(ws + off);           off = align_up(off + (size_t)(n + 1) * 4, 16);
    int* cnt = (int*)(ws + off);               off = align_up(off + (size_t)n * 4, 16);
    int* bsum = (int*)(ws + off);              off = align_up(off + (size_t)1024 * 4, 16);
    int* ecol = (int*)(ws + off);              off = align_up(off + (size_t)e * 4, 16);

    const int nb = (n + 255) / 256;       // scan blocks

    // CSR build (edges constant across layers -> build once per launch)
    hipMemsetAsync(cnt, 0, (size_t)n * 4, stream);
    hist_kernel<<<(e + 255) / 256, 256, 0, stream>>>(row, cnt, e);
    block_sum_kernel<<<nb, 256, 0, stream>>>(cnt, bsum, n);
    scan_bsum_kernel<<<1, 1024, 0, stream>>>(bsum, nb, row_ptr + n);  // total -> row_ptr[n]
    scan_final_kernel<<<nb, 256, 0, stream>>>(cnt, bsum, row_ptr, n);
    hipMemsetAsync(cnt, 0, (size_t)n * 4, stream);
    fill_kernel<<<1024, 256, 0, stream>>>(row, col, row_ptr, cnt, ecol, e, n);

    // pre-transpose weights to [k][o]
    transpose_kernel<<<(2 * L * 4096 + 255) / 256, 256, 0, stream>>>(conv_w, hid_w, wt, L);

    const int gemm_blocks = (n + NPB - 1) / NPB;
    const int agg_blocks = (n * 64 + 255) / 256;   // one wave per node
    const float* hin = x;
    for (int l = 0; l < L; l++) {
        mm_relu_kernel<<<gemm_blocks, 256, 0, stream>>>(hin, wt + (size_t)l * 4096, m, n);
        aggregate_kernel<<<agg_blocks, 256, 0, stream>>>(hin, m, row_ptr, ecol,
                                                         conv_nw + (size_t)l * HIDDEN, out, n);
        hidden_kernel<<<gemm_blocks, 256, 0, stream>>>(out, wt + (size_t)(L + l) * 4096,
                                                       hid_nw + (size_t)l * HIDDEN, n);
        hin = out;
    }
}

// Round 5
// 382.626 us; speedup vs baseline: 2.8804x; 1.2254x over previous
//
#include <hip/hip_runtime.h>
#include <hip/hip_bf16.h>

#define HIDDEN 64
#define EPS 1e-5f
#define NPB 64            // nodes per block in GEMM kernels
#define WST 72            // bf16 LDS row stride (64+8): keeps 16B align, breaks 128B bank aliasing

typedef __attribute__((ext_vector_type(8))) short bf16x8;   // 8 bf16 = 4 VGPRs (MFMA A/B frag)
typedef __attribute__((ext_vector_type(4))) float f32x4;    // MFMA C/D frag

__device__ __forceinline__ unsigned short f2b(float x) {
    __hip_bfloat16 b = __float2bfloat16(x);
    return *(unsigned short*)&b;
}

// ---------------- CSR build (XCD-partitioned: class = blockIdx&7 owns a row range,
// so each ecol/cnt cache line is dirtied by one XCD's L2 only) ----------------

__global__ __launch_bounds__(256) void hist_kernel(const int* __restrict__ row,
                                                   int* __restrict__ cnt, int e, int n) {
    int cls = blockIdx.x & 7;
    int sub = blockIdx.x >> 3;
    int nsub = gridDim.x >> 3;
    int lo = (int)(((long long)n * cls) >> 3);
    int hi = (int)(((long long)n * (cls + 1)) >> 3);
    for (int i = sub * 256 + threadIdx.x; i < e; i += nsub * 256) {
        int r = row[i];
        if (r >= lo && r < hi) atomicAdd(&cnt[r], 1);
    }
}

// per-block sums: bsum[b] = sum(cnt[b*256 .. b*256+255])
__global__ __launch_bounds__(256) void block_sum_kernel(const int* __restrict__ cnt,
                                                        int* __restrict__ bsum, int n) {
    __shared__ int wsum[4];
    int tid = threadIdx.x;
    int i = blockIdx.x * 256 + tid;
    int v = (i < n) ? cnt[i] : 0;
#pragma unroll
    for (int off = 32; off > 0; off >>= 1) v += __shfl_xor(v, off, 64);
    if ((tid & 63) == 0) wsum[tid >> 6] = v;
    __syncthreads();
    if (tid == 0) bsum[blockIdx.x] = wsum[0] + wsum[1] + wsum[2] + wsum[3];
}

// single block: exclusive scan of bsum[0..nb), total -> *total_out
__global__ __launch_bounds__(1024) void scan_bsum_kernel(int* __restrict__ bsum, int nb,
                                                         int* __restrict__ total_out) {
    __shared__ int wsum[16];
    __shared__ int wexcl[16];
    int tid = threadIdx.x;
    int lane = tid & 63;
    int w = tid >> 6;
    int v = (tid < nb) ? bsum[tid] : 0;
    int sc = v;
#pragma unroll
    for (int off = 1; off < 64; off <<= 1) {
        int t = __shfl_up(sc, off, 64);
        if (lane >= off) sc += t;
    }
    if (lane == 63) wsum[w] = sc;
    __syncthreads();
    if (tid == 0) {
        int a = 0;
#pragma unroll
        for (int j = 0; j < 16; j++) { wexcl[j] = a; a += wsum[j]; }
        *total_out = a;
    }
    __syncthreads();
    if (tid < nb) bsum[tid] = wexcl[w] + (sc - v);
}

// per-block scan + add block offset -> row_ptr
__global__ __launch_bounds__(256) void scan_final_kernel(const int* __restrict__ cnt,
                                                         const int* __restrict__ bexcl,
                                                         int* __restrict__ row_ptr, int n) {
    __shared__ int wsum[4];
    __shared__ int wexcl[4];
    int tid = threadIdx.x;
    int lane = tid & 63;
    int w = tid >> 6;
    int i = blockIdx.x * 256 + tid;
    int v = (i < n) ? cnt[i] : 0;
    int sc = v;
#pragma unroll
    for (int off = 1; off < 64; off <<= 1) {
        int t = __shfl_up(sc, off, 64);
        if (lane >= off) sc += t;
    }
    if (lane == 63) wsum[w] = sc;
    __syncthreads();
    if (tid == 0) {
        int a = 0;
#pragma unroll
        for (int j = 0; j < 4; j++) { wexcl[j] = a; a += wsum[j]; }
    }
    __syncthreads();
    if (i < n) row_ptr[i] = bexcl[blockIdx.x] + wexcl[w] + (sc - v);
}

__global__ __launch_bounds__(256) void fill_kernel(const int* __restrict__ row,
                                                   const int* __restrict__ col,
                                                   const int* __restrict__ row_ptr,
                                                   int* __restrict__ cnt,
                                                   int* __restrict__ ecol, int e, int n) {
    int cls = blockIdx.x & 7;
    int sub = blockIdx.x >> 3;
    int nsub = gridDim.x >> 3;
    int lo = (int)(((long long)n * cls) >> 3);
    int hi = (int)(((long long)n * (cls + 1)) >> 3);
    for (int i = sub * 256 + threadIdx.x; i < e; i += nsub * 256) {
        int r = row[i];
        if (r >= lo && r < hi) {
            int pos = row_ptr[r] + atomicAdd(&cnt[r], 1);
            ecol[pos] = col[i];
        }
    }
}

// ---------------- MFMA GEMM layer kernels ----------------
// Block: 256 threads = 4 waves, NPB=64 nodes. Wave w computes nodes w*16..w*16+15
// (M=16) x all 64 outputs (N=64) over K=64, via 8x mfma_f32_16x16x32_bf16.
// LDS: s_hb[node][k] bf16 (stride WST=72), s_wb[o][k] bf16 (weights already [o][k]
// row-major in global = MFMA B-frag k-contiguous layout; no transpose needed).

__device__ __forceinline__ void stage_gemm(const float* __restrict__ h,
                                           const float* __restrict__ w,
                                           unsigned short* s_hb, unsigned short* s_wb,
                                           int base, int n, int tid) {
    // weights: 64 rows x 8 segs of 8 floats
    for (int i = tid; i < 512; i += 256) {
        int r = i >> 3, seg = i & 7;
        const float4* wp = (const float4*)(w + r * 64 + seg * 8);
        float4 wa = wp[0], wb = wp[1];
        uint4 p;
        p.x = (unsigned int)f2b(wa.x) | ((unsigned int)f2b(wa.y) << 16);
        p.y = (unsigned int)f2b(wa.z) | ((unsigned int)f2b(wa.w) << 16);
        p.z = (unsigned int)f2b(wb.x) | ((unsigned int)f2b(wb.y) << 16);
        p.w = (unsigned int)f2b(wb.z) | ((unsigned int)f2b(wb.w) << 16);
        *(uint4*)(&s_wb[r * WST + seg * 8]) = p;
    }
    // h tile
    for (int i = tid; i < 512; i += 256) {
        int r = i >> 3, seg = i & 7;
        uint4 p = make_uint4(0u, 0u, 0u, 0u);
        if (base + r < n) {
            const float4* hp = (const float4*)(h + (size_t)(base + r) * HIDDEN + seg * 8);
            float4 ha = hp[0], hb = hp[1];
            p.x = (unsigned int)f2b(ha.x) | ((unsigned int)f2b(ha.y) << 16);
            p.y = (unsigned int)f2b(ha.z) | ((unsigned int)f2b(ha.w) << 16);
            p.z = (unsigned int)f2b(hb.x) | ((unsigned int)f2b(hb.y) << 16);
            p.w = (unsigned int)f2b(hb.z) | ((unsigned int)f2b(hb.w) << 16);
        }
        *(uint4*)(&s_hb[r * WST + seg * 8]) = p;
    }
}

#define MFMA_CORE(ACC)                                                          \
    int lane = threadIdx.x & 63;                                                \
    int wave = threadIdx.x >> 6;                                                \
    int quad = lane >> 4;                                                       \
    int l16 = lane & 15;                                                        \
    int wbase = wave * 16;                                                      \
    f32x4 ACC[4];                                                               \
    ACC[0] = (f32x4){0.f, 0.f, 0.f, 0.f}; ACC[1] = (f32x4){0.f, 0.f, 0.f, 0.f};\
    ACC[2] = (f32x4){0.f, 0.f, 0.f, 0.f}; ACC[3] = (f32x4){0.f, 0.f, 0.f, 0.f};\
    {                                                                           \
        const unsigned short* ap = &s_hb[(wbase + l16) * WST + quad * 8];       \
        const unsigned short* bp = &s_wb[l16 * WST + quad * 8];                 \
        _Pragma("unroll")                                                       \
        for (int kt = 0; kt < 2; kt++) {                                        \
            bf16x8 a = *(const bf16x8*)(ap + kt * 32);                          \
            _Pragma("unroll")                                                   \
            for (int nt = 0; nt < 4; nt++) {                                    \
                bf16x8 b = *(const bf16x8*)(bp + (size_t)nt * 16 * WST + kt * 32); \
                ACC[nt] = __builtin_amdgcn_mfma_f32_16x16x32_bf16(a, b, ACC[nt], 0, 0, 0); \
            }                                                                   \
        }                                                                       \
    }

// m[node] = bf16(relu(h[node] @ w^T))
__global__ __launch_bounds__(256) void mm_relu_kernel(const float* __restrict__ h,
                                                      const float* __restrict__ w,
                                                      __hip_bfloat16* __restrict__ m, int n) {
    __shared__ unsigned short s_hb[NPB * WST];
    __shared__ unsigned short s_wb[64 * WST];
    int tid = threadIdx.x;
    int base = blockIdx.x * NPB;
    stage_gemm(h, w, s_hb, s_wb, base, n, tid);
    __syncthreads();
    MFMA_CORE(acc)
    // D layout: col = l16 (output), row = quad*4 + r (node)
    unsigned short* mo = (unsigned short*)m;
#pragma unroll
    for (int r = 0; r < 4; r++) {
        int node = base + wbase + quad * 4 + r;
        if (node < n) {
#pragma unroll
            for (int nt = 0; nt < 4; nt++)
                mo[(size_t)node * HIDDEN + nt * 16 + l16] = f2b(fmaxf(acc[nt][r], 0.f));
        }
    }
}

// h[node] = rmsnorm(h[node] + relu(h[node] @ w^T), nw)  (in place; f32 residual from global)
__global__ __launch_bounds__(256) void hidden_kernel(float* __restrict__ h,
                                                     const float* __restrict__ w,
                                                     const float* __restrict__ nw, int n) {
    __shared__ unsigned short s_hb[NPB * WST];
    __shared__ unsigned short s_wb[64 * WST];
    int tid = threadIdx.x;
    int base = blockIdx.x * NPB;
    stage_gemm(h, w, s_hb, s_wb, base, n, tid);
    __syncthreads();
    MFMA_CORE(acc)
    float sv[4][4];
    float ssq[4] = {0.f, 0.f, 0.f, 0.f};
#pragma unroll
    for (int r = 0; r < 4; r++) {
        int node = base + wbase + quad * 4 + r;
        bool ok = node < n;
#pragma unroll
        for (int nt = 0; nt < 4; nt++) {
            float hres = ok ? h[(size_t)node * HIDDEN + nt * 16 + l16] : 0.f;
            float s = hres + fmaxf(acc[nt][r], 0.f);
            sv[r][nt] = s;
            ssq[r] += s * s;
        }
    }
    // reduce ssq across the 16 lanes sharing each row (xor within the 16-lane group)
#pragma unroll
    for (int mk = 1; mk <= 8; mk <<= 1) {
#pragma unroll
        for (int r = 0; r < 4; r++) ssq[r] += __shfl_xor(ssq[r], mk, 64);
    }
    float inv[4];
#pragma unroll
    for (int r = 0; r < 4; r++) inv[r] = rsqrtf(ssq[r] * (1.0f / 64.0f) + EPS);
    float nwv[4];
#pragma unroll
    for (int nt = 0; nt < 4; nt++) nwv[nt] = nw[nt * 16 + l16];
#pragma unroll
    for (int r = 0; r < 4; r++) {
        int node = base + wbase + quad * 4 + r;
        if (node < n) {
#pragma unroll
            for (int nt = 0; nt < 4; nt++)
                h[(size_t)node * HIDDEN + nt * 16 + l16] = sv[r][nt] * inv[r] * nwv[nt];
        }
    }
}

// ---------------- aggregation ----------------

// out[node] = rmsnorm(h[node] + sum_{e in CSR[node]} bf16 m[ecol[e]], nw)
// one wave per node, lane = channel; 8 unconditional gathers in flight
__global__ __launch_bounds__(256) void aggregate_kernel(const float* __restrict__ h,
                                                        const __hip_bfloat16* __restrict__ m,
                                                        const int* __restrict__ row_ptr,
                                                        const int* __restrict__ ecol,
                                                        const float* __restrict__ nw,
                                                        float* __restrict__ out, int n) {
    int lane = threadIdx.x & 63;
    int node = (blockIdx.x * blockDim.x + threadIdx.x) >> 6;
    if (node >= n) return;
    int beg = row_ptr[node];
    int end = row_ptr[node + 1];
    float hval = h[(size_t)node * HIDDEN + lane];
    float acc[8];
#pragma unroll
    for (int j = 0; j < 8; j++) acc[j] = 0.f;
    for (int base = beg; base < end; base += 8) {
        int c[8];
#pragma unroll
        for (int j = 0; j < 8; j++) {
            int idx = base + j;
            c[j] = ecol[idx < end ? idx : end - 1];
        }
        float v[8];
#pragma unroll
        for (int j = 0; j < 8; j++)
            v[j] = __bfloat162float(m[(size_t)c[j] * HIDDEN + lane]);
#pragma unroll
        for (int j = 0; j < 8; j++)
            acc[j] += (base + j < end) ? v[j] : 0.f;
    }
    float s = hval + (((acc[0] + acc[1]) + (acc[2] + acc[3])) +
                      ((acc[4] + acc[5]) + (acc[6] + acc[7])));
    float ss = s * s;
#pragma unroll
    for (int off = 32; off > 0; off >>= 1) ss += __shfl_xor(ss, off, 64);
    float inv = rsqrtf(ss * (1.0f / 64.0f) + EPS);
    out[(size_t)node * HIDDEN + lane] = s * inv * nw[lane];
}

// ---------------- launch ----------------

static inline size_t align_up(size_t x, size_t a) { return (x + a - 1) & ~(a - 1); }

extern "C" void kernel_launch(void* const* d_in, const int* in_sizes, int n_in,
                              void* d_out, int out_size, void* d_ws, size_t ws_size,
                              hipStream_t stream) {
    const float* x       = (const float*)d_in[0];
    const float* conv_w  = (const float*)d_in[1];
    const float* conv_nw = (const float*)d_in[2];
    const float* hid_w   = (const float*)d_in[3];
    const float* hid_nw  = (const float*)d_in[4];
    const int*   row     = (const int*)d_in[5];
    const int*   col     = (const int*)d_in[6];
    float* out = (float*)d_out;

    const int n = in_sizes[0] / HIDDEN;   // 100000
    const int e = in_sizes[5];            // 800000
    const int L = in_sizes[1] / 4096;     // 4

    // workspace layout
    size_t off = 0;
    char* ws = (char*)d_ws;
    __hip_bfloat16* m = (__hip_bfloat16*)(ws + off); off = align_up(off + (size_t)n * HIDDEN * 2, 16);
    int* row_ptr = (int*)(ws + off);           off = align_up(off + (size_t)(n + 1) * 4, 16);
    int* cnt = (int*)(ws + off);               off = align_up(off + (size_t)n * 4, 16);
    int* bsum = (int*)(ws + off);              off = align_up(off + (size_t)1024 * 4, 16);
    int* ecol = (int*)(ws + off);              off = align_up(off + (size_t)e * 4, 16);

    const int nb = (n + 255) / 256;       // scan blocks

    // CSR build (edges constant across layers -> build once per launch)
    hipMemsetAsync(cnt, 0, (size_t)n * 4, stream);
    hist_kernel<<<1024, 256, 0, stream>>>(row, cnt, e, n);
    block_sum_kernel<<<nb, 256, 0, stream>>>(cnt, bsum, n);
    scan_bsum_kernel<<<1, 1024, 0, stream>>>(bsum, nb, row_ptr + n);  // total -> row_ptr[n]
    scan_final_kernel<<<nb, 256, 0, stream>>>(cnt, bsum, row_ptr, n);
    hipMemsetAsync(cnt, 0, (size_t)n * 4, stream);
    fill_kernel<<<1024, 256, 0, stream>>>(row, col, row_ptr, cnt, ecol, e, n);

    const int gemm_blocks = (n + NPB - 1) / NPB;
    const int agg_blocks = (n * 64 + 255) / 256;   // one wave per node
    const float* hin = x;
    for (int l = 0; l < L; l++) {
        mm_relu_kernel<<<gemm_blocks, 256, 0, stream>>>(hin, conv_w + (size_t)l * 4096, m, n);
        aggregate_kernel<<<agg_blocks, 256, 0, stream>>>(hin, m, row_ptr, ecol,
                                                         conv_nw + (size_t)l * HIDDEN, out, n);
        hidden_kernel<<<gemm_blocks, 256, 0, stream>>>(out, hid_w + (size_t)l * 4096,
                                                       hid_nw + (size_t)l * HIDDEN, n);
        hin = out;
    }
}